// Round 16
// baseline (107.939 us; speedup 1.0000x reference)
//
#include <hip/hip_runtime.h>
#include <hip/hip_bf16.h>

#define NROW 8192
#define NF   128
#define LOG2E 1.4426950408889634f
#define NBM  ((NROW / 64) * (NROW / 512))   // 2048 bitmask blocks

typedef float f32x4  __attribute__((ext_vector_type(4)));
typedef int   i32x4  __attribute__((ext_vector_type(4)));
typedef short bf16x8 __attribute__((ext_vector_type(8)));
typedef short bf16x4 __attribute__((ext_vector_type(4)));
typedef unsigned long long u64;

__device__ __forceinline__ short f2bf(float f) {
    union { float f; unsigned u; } v; v.f = f;
    unsigned r = v.u + 0x7FFFu + ((v.u >> 16) & 1u);
    return (short)(r >> 16);
}

__device__ __forceinline__ void gload_lds16(const short* g, short* l) {
    __builtin_amdgcn_global_load_lds(
        (const __attribute__((address_space(1))) void*)g,
        (__attribute__((address_space(3))) void*)l, 16, 0, 0);
}

// Tiled B layout (LDS-image order): element (f, j) ->
//   (j>>6)*8192 + (f>>4)*1024 + ((j>>5)&1)*512 + ((j>>3)&3)*128 + (f&15)*8 + (j&7)

// k0: WT[c][k] = bf16(W[k][c])
__global__ __launch_bounds__(256) void k0_wt(const float* __restrict__ W,
                                             short* __restrict__ WT) {
    int idx = blockIdx.x * 256 + threadIdx.x;
    int c = idx >> 7, k = idx & 127;
    WT[c * NF + k] = f2bf(W[k * NF + c]);
}

// k1f: fused. Blocks [0,NBM): adj -> bm2 bitmask (u64 per (row, 64j-blk));
//      pure HBM streamer: coalesced reads, ballot transpose, 128B stores,
//      no LDS, no barriers, ~50 VGPR -> 24+ waves/CU, queue always full.
//      Blocks [NBM, NBM+256): Wh = mo@W -> tiled WhT, s1/s2 (rides along).
__global__ __launch_bounds__(256) void k1f(const float* __restrict__ mo,
        const short* __restrict__ WT, const float* __restrict__ a1,
        const float* __restrict__ a2, const int* __restrict__ adj,
        short* __restrict__ WhT, float* __restrict__ s1g, float* __restrict__ s2g,
        u64* __restrict__ bm2) {
    int t = threadIdx.x;
    if (blockIdx.x < NBM) {
        int bb = blockIdx.x;
        int rowgrp = bb >> 4, jseg16 = bb & 15;    // 64 rows x 512 j per block
        int w = t >> 6, l = t & 63, lo = l & 15;
        int wrows0 = rowgrp * 64 + w * 16;
        const int* arow = adj + (size_t)wrows0 * NROW + jseg16 * 512 + l;

        int An[16];
#pragma unroll
        for (int r = 0; r < 16; ++r) An[r] = arow[r * NROW];
        for (int it = 0; it < 8; ++it) {
            u64 bmq = 0;
            int more = (it + 1 < 8);
#pragma unroll
            for (int r = 0; r < 16; ++r) {
                u64 br = __ballot(An[r] > 0);
                if (more) An[r] = arow[r * NROW + ((it + 1) << 6)];
                bmq = (lo == r) ? br : bmq;
            }
            if (l < 16)
                bm2[(size_t)(jseg16 * 8 + it) * NROW + wrows0 + lo] = bmq;
        }
        return;
    }
    // ---- Wh part ----
    __shared__ float s_lds[2][32];
    int w = t >> 6, l = t & 63, lg = l >> 4, lr = l & 15;
    int rows0 = (blockIdx.x - NBM) * 32;
    if (t < 64) s_lds[t >> 5][t & 31] = 0.0f;
    __syncthreads();

    f32x4 acc[2][2] = {};
#pragma unroll
    for (int ks = 0; ks < 4; ++ks) {
        bf16x8 a[2], b[2];
#pragma unroll
        for (int rt = 0; rt < 2; ++rt) {
            const float* ap = mo + (size_t)(rows0 + rt*16 + lr) * NF + ks*32 + lg*8;
            f32x4 x0 = *(const f32x4*)ap;
            f32x4 x1 = *(const f32x4*)(ap + 4);
#pragma unroll
            for (int e = 0; e < 4; ++e) { a[rt][e] = f2bf(x0[e]); a[rt][4+e] = f2bf(x1[e]); }
        }
#pragma unroll
        for (int ct = 0; ct < 2; ++ct) {
            int c = w*32 + ct*16 + lr;
            b[ct] = *(const bf16x8*)(WT + c*NF + ks*32 + lg*8);
        }
#pragma unroll
        for (int rt = 0; rt < 2; ++rt)
#pragma unroll
            for (int ct = 0; ct < 2; ++ct)
                acc[rt][ct] = __builtin_amdgcn_mfma_f32_16x16x32_bf16(a[rt], b[ct], acc[rt][ct], 0, 0, 0);
    }

    // C/D layout: col = lane&15, row = (lane>>4)*4 + reg
#pragma unroll
    for (int rt = 0; rt < 2; ++rt) {
        float p1[4] = {0,0,0,0}, p2[4] = {0,0,0,0};
#pragma unroll
        for (int ct = 0; ct < 2; ++ct) {
            int c = w*32 + ct*16 + lr;
            float a1c = a1[c], a2c = a2[c];
            bf16x4 wv;
#pragma unroll
            for (int g = 0; g < 4; ++g) {
                float v = acc[rt][ct][g];
                wv[g] = f2bf(v);
                p1[g] += v * a1c;
                p2[g] += v * a2c;
            }
            int r0 = rows0 + rt*16 + lg*4;   // multiple of 4
            size_t off = (size_t)(r0 >> 6) * 8192 + (size_t)(c >> 4) * 1024
                       + (size_t)((r0 >> 5) & 1) * 512 + (size_t)((r0 >> 3) & 3) * 128
                       + (size_t)(c & 15) * 8 + (size_t)(r0 & 7);
            *(bf16x4*)(WhT + off) = wv;
        }
#pragma unroll
        for (int off = 1; off < 16; off <<= 1) {
#pragma unroll
            for (int g = 0; g < 4; ++g) {
                p1[g] += __shfl_xor(p1[g], off);
                p2[g] += __shfl_xor(p2[g], off);
            }
        }
        if (lr == 0) {
            int rloc = rt*16 + lg*4;
#pragma unroll
            for (int g = 0; g < 4; ++g) {
                atomicAdd(&s_lds[0][rloc+g], p1[g]);
                atomicAdd(&s_lds[1][rloc+g], p2[g]);
            }
        }
    }
    __syncthreads();
    if (t < 32)       s1g[rows0 + t]        = s_lds[0][t] * LOG2E;
    else if (t < 64)  s2g[rows0 + (t - 32)] = s_lds[1][t - 32] * LOG2E;
}

// k2: pure compute. 4 waves x 16 disjoint rows, one j-segment (npb<=1024).
// bm slice (npb u64 = 8KB) + s2 slice staged ONCE into LDS at start -> the
// main loop's only global traffic is the B-tile stage (gload_lds, L2-hot).
// Per 64-j iteration: 1 ds_read_b64 (mask) + exp straight into A-frags +
// 16 MFMA from LDS B. LDS 28.2KB; (256,4) -> 16 waves/CU, no spill.
__global__ __launch_bounds__(256, 4) void k2_main(
        const u64* __restrict__ bm2, const short* __restrict__ WhT,
        const float* __restrict__ s1g, const float* __restrict__ s2g,
        float* __restrict__ numP, float* __restrict__ zP,
        int S, int npb) {
    __shared__ __attribute__((aligned(16))) short Bl[8192];   // 16KB B tile
    __shared__ __attribute__((aligned(16))) float s2l[1024];  // 4KB
    __shared__ __attribute__((aligned(16))) u64  bml[1024];   // 8KB

    int t = threadIdx.x, w = t >> 6, l = t & 63;
    int lo = l & 15, hi = l >> 4;
    int b = blockIdx.x, jseg = b % S, rg = b / S;
    int wrows0 = (rg << 6) + (w << 4);
    int j0 = jseg * npb;
    int NT = npb >> 6;
    int jb0 = j0 >> 6;

    // stage s2 slice (npb floats)
    for (int i = t; i < (npb >> 2); i += 256)
        ((f32x4*)s2l)[i] = ((const f32x4*)(s2g + j0))[i];
    // stage bm slice (npb u64): f..f+3 share one jblk (f%64+3 <= 63)
    for (int f = t * 4; f < npb; f += 1024) {
        const u64* g = bm2 + (size_t)(jb0 + (f >> 6)) * NROW + (rg << 6) + (f & 63);
        *(i32x4*)(bml + f)     = *(const i32x4*)g;
        *(i32x4*)(bml + f + 2) = *(const i32x4*)(g + 2);
    }
    {   // stage B tile 0 (each of 4 waves stages its 4KB quarter)
        const short* gs = WhT + (size_t)jb0 * 8192 + w*2048 + l*8;
        short* ds = &Bl[w*2048];
#pragma unroll
        for (int r4 = 0; r4 < 4; ++r4)
            gload_lds16(gs + r4*512, ds + r4*512);
    }
    __syncthreads();

    float s1v = s1g[wrows0 + lo];
    f32x4 acc[8] = {};
    float z = 0.0f;

    for (int it = 0; it < NT; ++it) {
        u64 bmq = bml[it * 64 + w * 16 + lo];   // broadcast across hi-groups
#pragma unroll
        for (int ks = 0; ks < 2; ++ks) {
            unsigned bits = (unsigned)(bmq >> ((ks << 5) + hi * 8)) & 0xffu;
            int js = (it << 6) + ks * 32 + hi * 8;
            f32x4 sa = *(const f32x4*)(s2l + js);
            f32x4 sb = *(const f32x4*)(s2l + js + 4);
            float p[8];
#pragma unroll
            for (int e = 0; e < 4; ++e) {
                float x, pe;
                x = s1v + sa[e]; pe = exp2f(fmaxf(x, 0.2f * x));
                p[e]     = ((bits >> e) & 1) ? pe : 0.0f;        z += p[e];
                x = s1v + sb[e]; pe = exp2f(fmaxf(x, 0.2f * x));
                p[4 + e] = ((bits >> (4 + e)) & 1) ? pe : 0.0f;  z += p[4 + e];
            }
            union { bf16x8 v8; __hip_bfloat162 h2[4]; } fau;
#pragma unroll
            for (int q = 0; q < 4; ++q)
                fau.h2[q] = __float22bfloat162_rn(make_float2(p[2*q], p[2*q + 1]));
            const short* Bc = &Bl[ks * 512 + l * 8];
#pragma unroll
            for (int ct = 0; ct < 8; ++ct) {
                bf16x8 bv = *(const bf16x8*)(Bc + ct * 1024);
                acc[ct] = __builtin_amdgcn_mfma_f32_16x16x32_bf16(fau.v8, bv, acc[ct], 0, 0, 0);
            }
        }
        __syncthreads();            // all waves done reading Bl
        if (it + 1 < NT) {          // stage next tile (L2-hot, ~300cy exposed)
            const short* gs = WhT + (size_t)(jb0 + it + 1) * 8192 + w*2048 + l*8;
            short* ds = &Bl[w*2048];
#pragma unroll
            for (int r4 = 0; r4 < 4; ++r4)
                gload_lds16(gs + r4*512, ds + r4*512);
            __syncthreads();        // stage complete (vmcnt(0) via syncthreads)
        }
    }

    // --- epilogue: disjoint rows per wave -> direct stores, no reduction ---
    z += __shfl_xor(z, 16);
    z += __shfl_xor(z, 32);
    if (l < 16) zP[(size_t)jseg * NROW + wrows0 + lo] = z;

    size_t obase = (size_t)jseg * NROW * NF;
#pragma unroll
    for (int ct = 0; ct < 8; ++ct) {
        int cc = ct * 16 + lo;
        int r0 = wrows0 + hi * 4;
#pragma unroll
        for (int g = 0; g < 4; ++g)
            numP[obase + (size_t)(r0 + g) * NF + cc] = acc[ct][g];
    }
}

// k3: out = elu( sum_s num / sum_s z ), vectorized x4
__global__ __launch_bounds__(256) void k3_reduce(const float* __restrict__ numP,
        const float* __restrict__ zP, float* __restrict__ out, int S) {
    int idx = (blockIdx.x * 256 + threadIdx.x) * 4;
    int r = idx >> 7;
    f32x4 num = {};
    float zz = 0.0f;
    for (int s = 0; s < S; ++s) {
        f32x4 v = *(const f32x4*)(numP + (size_t)s * (NROW * NF) + idx);
        num += v;
        zz  += zP[s * NROW + r];
    }
    f32x4 o;
#pragma unroll
    for (int e = 0; e < 4; ++e) {
        float h = num[e] / zz;
        o[e] = (h > 0.0f) ? h : expm1f(h);
    }
    *(f32x4*)(out + idx) = o;
}

extern "C" void kernel_launch(void* const* d_in, const int* in_sizes, int n_in,
                              void* d_out, int out_size, void* d_ws, size_t ws_size,
                              hipStream_t stream) {
    const float* mo  = (const float*)d_in[0];
    const int*   adj = (const int*)d_in[1];
    const float* W   = (const float*)d_in[2];
    const float* a1  = (const float*)d_in[3];
    const float* a2  = (const float*)d_in[4];
    float* out = (float*)d_out;

    char* p = (char*)d_ws;
    short* WT  = (short*)p;  p += (size_t)NF * NF * 2;
    short* WhT = (short*)p;  p += (size_t)NF * NROW * 2;
    float* s1  = (float*)p;  p += (size_t)NROW * 4;
    float* s2  = (float*)p;  p += (size_t)NROW * 4;
    float* zP  = (float*)p;  p += (size_t)8 * NROW * 4;           // S<=8
    u64*  bm2  = (u64*)p;    p += (size_t)(NROW / 64) * NROW * 8; // 8MB
    size_t fixed = (size_t)(p - (char*)d_ws);

    int S = 8;   // npb=1024 (k2 LDS arrays sized for npb<=1024); ws ~1GB
    float* numP = (float*)p;
    if (fixed + (size_t)S * NROW * NF * 4 > ws_size) numP = out;  // safety (ws is ~1GB)

    k0_wt<<<dim3(64), dim3(256), 0, stream>>>(W, WT);
    k1f<<<dim3(NBM + 256), dim3(256), 0, stream>>>(mo, WT, a1, a2, adj, WhT, s1, s2, bm2);
    k2_main<<<dim3((NROW / 64) * S), dim3(256), 0, stream>>>(bm2, WhT, s1, s2, numP, zP, S, NROW / S);
    k3_reduce<<<dim3(NROW * NF / 1024), dim3(256), 0, stream>>>(numP, zP, out, S);
}